// Round 2
// baseline (2188.475 us; speedup 1.0000x reference)
//
#include <hip/hip_runtime.h>
#include <cstdint>
#include <cstddef>

// ---------------- problem constants ----------------
#define D_MODEL   1024
#define D_STATE   16
#define D_CONV    4
#define D_INNER   2048
#define DT_RANK   64
#define NBATCH    2
#define SEQ       2048
#define NTOK      (NBATCH*SEQ)     // 4096 tokens
#define LN_EPSF   1e-5f

typedef unsigned short u16;
typedef __bf16 bf16x8 __attribute__((ext_vector_type(8)));
typedef float  f32x4  __attribute__((ext_vector_type(4)));

__device__ __forceinline__ u16 f2bf(float f) {
  unsigned u = __float_as_uint(f);
  u += 0x7fffu + ((u >> 16) & 1u);          // round-to-nearest-even
  return (u16)(u >> 16);
}
__device__ __forceinline__ float bf2f(u16 v) {
  return __uint_as_float(((unsigned)v) << 16);
}

// async global->LDS, 16B per lane; lds dest must be wave-uniform base (+lane*16)
__device__ __forceinline__ void async16(const u16* g, u16* l) {
  __builtin_amdgcn_global_load_lds(
      (const __attribute__((address_space(1))) unsigned*)g,
      (__attribute__((address_space(3))) unsigned*)l, 16, 0, 0);
}

// ---------------- f32 -> bf16 convert ----------------
__global__ void f32_to_bf16_k(const float* __restrict__ src, u16* __restrict__ dst, int n) {
  int i = blockIdx.x * 256 + threadIdx.x;
  if (i < n) dst[i] = f2bf(src[i]);
}

// ---------------- bf16 NT GEMM: C[M,N] = A[M,K] * B[N,K]^T ----------------
// EPI: 0 = store f32, 1 = store bf16, 2 = softplus(acc + bias[col]) f32, 3 = acc + res f32
template<int BM, int BN, int WTM, int WTN, int EPI>
__global__ __launch_bounds__(256) void gemm_nt(
    const u16* __restrict__ A, const u16* __restrict__ B,
    float* __restrict__ C, u16* __restrict__ Cb,
    const float* __restrict__ bias, const float* __restrict__ res,
    int K, int lda, int ldb, int ldc)
{
  constexpr int BK = 32;
  constexpr int WAVES_N = BN / (16 * WTN);
  constexpr int ACH = BM * 4;             // 16B chunks in A tile (BK=32 bf16 = 4 chunks/row)
  constexpr int BCH = BN * 4;
  constexpr int ROUNDS = (ACH + BCH) / 256;

  __shared__ __align__(16) u16 lA[BM * BK];
  __shared__ __align__(16) u16 lB[BN * BK];

  const int tid  = threadIdx.x;
  const int w    = tid >> 6;
  const int lane = tid & 63;
  const int lrow = lane & 15;
  const int quad = lane >> 4;
  const int bm = blockIdx.y * BM;
  const int bn = blockIdx.x * BN;
  const int wave_m = (w / WAVES_N) * (16 * WTM);
  const int wave_n = (w % WAVES_N) * (16 * WTN);

  f32x4 acc[WTM][WTN];
  #pragma unroll
  for (int mi = 0; mi < WTM; ++mi)
    #pragma unroll
    for (int ni = 0; ni < WTN; ++ni)
      acc[mi][ni] = (f32x4){0.f, 0.f, 0.f, 0.f};

  for (int k0 = 0; k0 < K; k0 += BK) {
    #pragma unroll
    for (int r = 0; r < ROUNDS; ++r) {
      const int c0 = r * 256 + w * 64;    // wave-uniform chunk base
      const int c  = c0 + lane;
      if (c0 < ACH) {
        const int row = c >> 2, cc = c & 3;
        async16(A + (size_t)(bm + row) * lda + k0 + cc * 8, &lA[c0 * 8]);
      } else {
        const int cb = c - ACH, c0b = c0 - ACH;
        const int row = cb >> 2, cc = cb & 3;
        async16(B + (size_t)(bn + row) * ldb + k0 + cc * 8, &lB[c0b * 8]);
      }
    }
    __syncthreads();   // drain global_load_lds + join

    bf16x8 af[WTM], bfv[WTN];
    #pragma unroll
    for (int mi = 0; mi < WTM; ++mi)
      af[mi] = *(const bf16x8*)&lA[(wave_m + mi * 16 + lrow) * BK + quad * 8];
    #pragma unroll
    for (int ni = 0; ni < WTN; ++ni)
      bfv[ni] = *(const bf16x8*)&lB[(wave_n + ni * 16 + lrow) * BK + quad * 8];
    #pragma unroll
    for (int mi = 0; mi < WTM; ++mi)
      #pragma unroll
      for (int ni = 0; ni < WTN; ++ni)
        acc[mi][ni] = __builtin_amdgcn_mfma_f32_16x16x32_bf16(af[mi], bfv[ni], acc[mi][ni], 0, 0, 0);
    __syncthreads();   // all waves done reading before next overwrite
  }

  #pragma unroll
  for (int mi = 0; mi < WTM; ++mi) {
    #pragma unroll
    for (int ni = 0; ni < WTN; ++ni) {
      const int col  = bn + wave_n + ni * 16 + lrow;
      const int row0 = bm + wave_m + mi * 16 + quad * 4;
      #pragma unroll
      for (int r = 0; r < 4; ++r) {
        float v = acc[mi][ni][r];
        const size_t idx = (size_t)(row0 + r) * ldc + col;
        if constexpr (EPI == 0) {
          C[idx] = v;
        } else if constexpr (EPI == 1) {
          Cb[idx] = f2bf(v);
        } else if constexpr (EPI == 2) {
          v += bias[col];
          v = (v > 20.f) ? v : log1pf(__expf(v));   // softplus
          C[idx] = v;
        } else {
          C[idx] = v + res[idx];
        }
      }
    }
  }
}

// ---------------- causal depthwise conv (D_CONV=4) + SiLU -> bf16 ----------------
__global__ void conv_silu_k(const float* __restrict__ xz, const float* __restrict__ Wc,
                            const float* __restrict__ bc, u16* __restrict__ ub)
{
  const int gid = blockIdx.x * 256 + threadIdx.x;       // over NTOK*D_INNER
  const int e   = gid & (D_INNER - 1);
  const int tok = gid >> 11;                            // D_INNER = 2^11
  const int l   = tok & (SEQ - 1);
  float acc = bc[e];
  #pragma unroll
  for (int j = 0; j < D_CONV; ++j) {
    const int li = l - 3 + j;
    if (li >= 0) acc += xz[(size_t)(tok - 3 + j) * (2 * D_INNER) + e] * Wc[e * D_CONV + j];
  }
  const float s = acc / (1.f + __expf(-acc));           // silu
  ub[gid] = f2bf(s);
}

// ---------------- selective scan, one lane per (b,e,n) ----------------
__global__ __launch_bounds__(256) void scan_k(
    const float* __restrict__ delta, const u16* __restrict__ ub,
    const u16* __restrict__ xdb, const float* __restrict__ xz,
    const float* __restrict__ A_log, const float* __restrict__ D_skip,
    u16* __restrict__ yg)
{
  const int tid = blockIdx.x * 256 + threadIdx.x;       // 65536 threads
  const int n  = tid & 15;
  const int ch = tid >> 4;                              // b*D_INNER + e
  const int e  = ch & (D_INNER - 1);
  const int b  = ch >> 11;
  const float Aen = -__expf(A_log[e * D_STATE + n]);
  const float De  = D_skip[e];
  const size_t base_du = (size_t)b * SEQ * D_INNER + e;       // + t*D_INNER
  const size_t base_z  = (size_t)b * SEQ * (2 * D_INNER) + D_INNER + e; // + t*2*D_INNER
  const size_t base_bc = (size_t)b * SEQ * 128;               // + t*128
  float h = 0.f;
  for (int t = 0; t < SEQ; ++t) {
    const float dlt = delta[base_du + (size_t)t * D_INNER];
    const float ut  = bf2f(ub[base_du + (size_t)t * D_INNER]);
    const float Bt  = bf2f(xdb[base_bc + t * 128 + DT_RANK + n]);
    const float Ct  = bf2f(xdb[base_bc + t * 128 + DT_RANK + D_STATE + n]);
    h = __expf(dlt * Aen) * h + dlt * Bt * ut;
    float p = h * Ct;
    p += __shfl_xor(p, 1); p += __shfl_xor(p, 2);
    p += __shfl_xor(p, 4); p += __shfl_xor(p, 8);
    if (n == 0) {
      const float z = xz[base_z + (size_t)t * (2 * D_INNER)];
      const float y = p + ut * De;
      const float g = z / (1.f + __expf(-z));
      yg[(size_t)(b * SEQ + t) * D_INNER + e] = f2bf(y * g);
    }
  }
}

// ---------------- LayerNorm, one block per token ----------------
__global__ __launch_bounds__(256) void ln_k(const float* __restrict__ pre,
                                            const float* __restrict__ gamma,
                                            const float* __restrict__ beta,
                                            float* __restrict__ out)
{
  const int tok = blockIdx.x;
  const int t   = threadIdx.x;
  const float* row = pre + (size_t)tok * D_MODEL;
  float v[4], s = 0.f, s2 = 0.f;
  #pragma unroll
  for (int i = 0; i < 4; ++i) {
    v[i] = row[t + i * 256];
    s += v[i]; s2 += v[i] * v[i];
  }
  #pragma unroll
  for (int off = 32; off >= 1; off >>= 1) {
    s  += __shfl_xor(s,  off);
    s2 += __shfl_xor(s2, off);
  }
  __shared__ float red[8];
  if ((t & 63) == 0) { red[t >> 6] = s; red[4 + (t >> 6)] = s2; }
  __syncthreads();
  if (t == 0) {
    const float ts  = red[0] + red[1] + red[2] + red[3];
    const float ts2 = red[4] + red[5] + red[6] + red[7];
    const float mu  = ts * (1.f / D_MODEL);
    const float var = ts2 * (1.f / D_MODEL) - mu * mu;
    red[0] = mu; red[1] = rsqrtf(var + LN_EPSF);
  }
  __syncthreads();
  const float mu = red[0], rv = red[1];
  #pragma unroll
  for (int i = 0; i < 4; ++i) {
    const int c = t + i * 256;
    out[(size_t)tok * D_MODEL + c] = (v[i] - mu) * rv * gamma[c] + beta[c];
  }
}

// ---------------- host launch ----------------
extern "C" void kernel_launch(void* const* d_in, const int* in_sizes, int n_in,
                              void* d_out, int out_size, void* d_ws, size_t ws_size,
                              hipStream_t stream) {
  const float* x       = (const float*)d_in[0];
  const float* W_in    = (const float*)d_in[1];
  const float* W_conv  = (const float*)d_in[2];
  const float* b_conv  = (const float*)d_in[3];
  const float* W_xproj = (const float*)d_in[4];
  const float* W_dt    = (const float*)d_in[5];
  const float* b_dt    = (const float*)d_in[6];
  const float* A_log   = (const float*)d_in[7];
  const float* D_skip  = (const float*)d_in[8];
  const float* W_out   = (const float*)d_in[9];
  const float* gamma   = (const float*)d_in[10];
  const float* beta    = (const float*)d_in[11];
  float* out = (float*)d_out;

  // workspace carve-up (256B aligned)
  char* ws = (char*)d_ws;
  size_t used = 0;
  auto alloc = [&](size_t bytes) -> char* {
    char* p = ws + used;
    used += (bytes + 255) & ~(size_t)255;
    return p;
  };
  float* xz      = (float*)alloc((size_t)NTOK * 2 * D_INNER * 4);   // 67 MB
  float* delta   = (float*)alloc((size_t)NTOK * D_INNER * 4);       // 33.5 MB
  float* pre     = (float*)alloc((size_t)NTOK * D_MODEL * 4);       // 16.8 MB
  u16* x_bf      = (u16*)alloc((size_t)NTOK * D_MODEL * 2);         // 8.4 MB
  u16* Win_bf    = (u16*)alloc((size_t)2 * D_INNER * D_MODEL * 2);  // 8.4 MB
  u16* u_bf      = (u16*)alloc((size_t)NTOK * D_INNER * 2);         // 16.8 MB
  u16* xdb_bf    = (u16*)alloc((size_t)NTOK * 128 * 2);             // 1 MB (96 padded to 128)
  u16* Wxp_bf    = (u16*)alloc((size_t)128 * D_INNER * 2);          // 0.5 MB
  u16* Wdt_bf    = (u16*)alloc((size_t)D_INNER * DT_RANK * 2);      // 0.26 MB
  u16* Wout_bf   = (u16*)alloc((size_t)D_MODEL * D_INNER * 2);      // 4.2 MB
  u16* yg_bf     = (u16*)alloc((size_t)NTOK * D_INNER * 2);         // 16.8 MB

  if (ws_size < used) {   // signal: NaN output (insufficient workspace)
    hipMemsetAsync(d_out, 0xFF, (size_t)out_size * 4, stream);
    return;
  }

  const dim3 blk(256);

  // conversions to bf16
  f32_to_bf16_k<<<(NTOK * D_MODEL + 255) / 256, blk, 0, stream>>>(x, x_bf, NTOK * D_MODEL);
  f32_to_bf16_k<<<(2 * D_INNER * D_MODEL + 255) / 256, blk, 0, stream>>>(W_in, Win_bf, 2 * D_INNER * D_MODEL);
  hipMemsetAsync(Wxp_bf, 0, (size_t)128 * D_INNER * 2, stream);
  f32_to_bf16_k<<<(96 * D_INNER + 255) / 256, blk, 0, stream>>>(W_xproj, Wxp_bf, 96 * D_INNER);
  f32_to_bf16_k<<<(D_INNER * DT_RANK + 255) / 256, blk, 0, stream>>>(W_dt, Wdt_bf, D_INNER * DT_RANK);
  f32_to_bf16_k<<<(D_MODEL * D_INNER + 255) / 256, blk, 0, stream>>>(W_out, Wout_bf, D_MODEL * D_INNER);

  // 1) in_proj: xz[4096,4096] = x[4096,1024] * W_in[4096,1024]^T
  gemm_nt<128,128,4,4,0><<<dim3((2*D_INNER)/128, NTOK/128), blk, 0, stream>>>(
      x_bf, Win_bf, xz, nullptr, nullptr, nullptr, D_MODEL, D_MODEL, D_MODEL, 2*D_INNER);

  // 2) causal depthwise conv + silu -> u (bf16)
  conv_silu_k<<<(NTOK * D_INNER) / 256, blk, 0, stream>>>(xz, W_conv, b_conv, u_bf);

  // 3) x_proj: xdb[4096,128(pad)] = u * W_xproj^T  (bf16 out)
  gemm_nt<64,128,1,8,1><<<dim3(1, NTOK/64), blk, 0, stream>>>(
      u_bf, Wxp_bf, nullptr, xdb_bf, nullptr, nullptr, D_INNER, D_INNER, D_INNER, 128);

  // 4) dt_proj + bias + softplus: delta[4096,2048] = softplus(dt * W_dt^T + b_dt)
  gemm_nt<128,128,4,4,2><<<dim3(D_INNER/128, NTOK/128), blk, 0, stream>>>(
      xdb_bf, Wdt_bf, delta, nullptr, b_dt, nullptr, DT_RANK, 128, DT_RANK, D_INNER);

  // 5) selective scan + skip + gate -> yg (bf16)
  scan_k<<<(NBATCH * D_INNER * D_STATE) / 256, blk, 0, stream>>>(
      delta, u_bf, xdb_bf, xz, A_log, D_skip, yg_bf);

  // 6) out_proj + residual: pre[4096,1024] = yg * W_out^T + x
  gemm_nt<128,128,4,4,3><<<dim3(D_MODEL/128, NTOK/128), blk, 0, stream>>>(
      yg_bf, Wout_bf, pre, nullptr, nullptr, x, D_INNER, D_INNER, D_INNER, D_MODEL);

  // 7) LayerNorm
  ln_k<<<NTOK, blk, 0, stream>>>(pre, gamma, beta, out);
}

// Round 3
// 402.709 us; speedup vs baseline: 5.4344x; 5.4344x over previous
//
#include <hip/hip_runtime.h>
#include <cstdint>
#include <cstddef>

// ---------------- problem constants ----------------
#define D_MODEL   1024
#define D_STATE   16
#define D_CONV    4
#define D_INNER   2048
#define DT_RANK   64
#define NBATCH    2
#define SEQ       2048
#define NTOK      (NBATCH*SEQ)     // 4096 tokens
#define LN_EPSF   1e-5f
#define NCHUNK    64
#define TCHUNK    32               // SEQ / NCHUNK

typedef unsigned short u16;
typedef __bf16 bf16x8 __attribute__((ext_vector_type(8)));
typedef float  f32x4  __attribute__((ext_vector_type(4)));

__device__ __forceinline__ u16 f2bf(float f) {
  unsigned u = __float_as_uint(f);
  u += 0x7fffu + ((u >> 16) & 1u);          // round-to-nearest-even
  return (u16)(u >> 16);
}
__device__ __forceinline__ float bf2f(u16 v) {
  return __uint_as_float(((unsigned)v) << 16);
}
// unpack 8 bf16 (packed in uint4) -> 8 floats
__device__ __forceinline__ void unpack8(uint4 v, float* f) {
  f[0] = __uint_as_float(v.x << 16); f[1] = __uint_as_float(v.x & 0xffff0000u);
  f[2] = __uint_as_float(v.y << 16); f[3] = __uint_as_float(v.y & 0xffff0000u);
  f[4] = __uint_as_float(v.z << 16); f[5] = __uint_as_float(v.z & 0xffff0000u);
  f[6] = __uint_as_float(v.w << 16); f[7] = __uint_as_float(v.w & 0xffff0000u);
}

// async global->LDS, 16B per lane; lds dest must be wave-uniform base (+lane*16)
__device__ __forceinline__ void async16(const u16* g, u16* l) {
  __builtin_amdgcn_global_load_lds(
      (const __attribute__((address_space(1))) unsigned*)g,
      (__attribute__((address_space(3))) unsigned*)l, 16, 0, 0);
}

// ---------------- f32 -> bf16 convert ----------------
__global__ void f32_to_bf16_k(const float* __restrict__ src, u16* __restrict__ dst, int n) {
  int i = blockIdx.x * 256 + threadIdx.x;
  if (i < n) dst[i] = f2bf(src[i]);
}

// ---------------- bf16 NT GEMM: C[M,N] = A[M,K] * B[N,K]^T ----------------
// EPI: 0 = store f32, 1 = store bf16, 2 = softplus(acc + bias[col]) -> bf16, 3 = acc + res f32
template<int BM, int BN, int WTM, int WTN, int EPI>
__global__ __launch_bounds__(256) void gemm_nt(
    const u16* __restrict__ A, const u16* __restrict__ B,
    float* __restrict__ C, u16* __restrict__ Cb,
    const float* __restrict__ bias, const float* __restrict__ res,
    int K, int lda, int ldb, int ldc)
{
  constexpr int BK = 32;
  constexpr int WAVES_N = BN / (16 * WTN);
  constexpr int ACH = BM * 4;             // 16B chunks in A tile (BK=32 bf16 = 4 chunks/row)
  constexpr int BCH = BN * 4;
  constexpr int ROUNDS = (ACH + BCH) / 256;

  __shared__ __align__(16) u16 lA[BM * BK];
  __shared__ __align__(16) u16 lB[BN * BK];

  const int tid  = threadIdx.x;
  const int w    = tid >> 6;
  const int lane = tid & 63;
  const int lrow = lane & 15;
  const int quad = lane >> 4;
  const int bm = blockIdx.y * BM;
  const int bn = blockIdx.x * BN;
  const int wave_m = (w / WAVES_N) * (16 * WTM);
  const int wave_n = (w % WAVES_N) * (16 * WTN);

  f32x4 acc[WTM][WTN];
  #pragma unroll
  for (int mi = 0; mi < WTM; ++mi)
    #pragma unroll
    for (int ni = 0; ni < WTN; ++ni)
      acc[mi][ni] = (f32x4){0.f, 0.f, 0.f, 0.f};

  for (int k0 = 0; k0 < K; k0 += BK) {
    #pragma unroll
    for (int r = 0; r < ROUNDS; ++r) {
      const int c0 = r * 256 + w * 64;    // wave-uniform chunk base
      const int c  = c0 + lane;
      if (c0 < ACH) {
        const int row = c >> 2, cc = c & 3;
        async16(A + (size_t)(bm + row) * lda + k0 + cc * 8, &lA[c0 * 8]);
      } else {
        const int cb = c - ACH, c0b = c0 - ACH;
        const int row = cb >> 2, cc = cb & 3;
        async16(B + (size_t)(bn + row) * ldb + k0 + cc * 8, &lB[c0b * 8]);
      }
    }
    __syncthreads();   // drain global_load_lds + join

    bf16x8 af[WTM], bfv[WTN];
    #pragma unroll
    for (int mi = 0; mi < WTM; ++mi)
      af[mi] = *(const bf16x8*)&lA[(wave_m + mi * 16 + lrow) * BK + quad * 8];
    #pragma unroll
    for (int ni = 0; ni < WTN; ++ni)
      bfv[ni] = *(const bf16x8*)&lB[(wave_n + ni * 16 + lrow) * BK + quad * 8];
    #pragma unroll
    for (int mi = 0; mi < WTM; ++mi)
      #pragma unroll
      for (int ni = 0; ni < WTN; ++ni)
        acc[mi][ni] = __builtin_amdgcn_mfma_f32_16x16x32_bf16(af[mi], bfv[ni], acc[mi][ni], 0, 0, 0);
    __syncthreads();   // all waves done reading before next overwrite
  }

  #pragma unroll
  for (int mi = 0; mi < WTM; ++mi) {
    #pragma unroll
    for (int ni = 0; ni < WTN; ++ni) {
      const int col  = bn + wave_n + ni * 16 + lrow;
      const int row0 = bm + wave_m + mi * 16 + quad * 4;
      #pragma unroll
      for (int r = 0; r < 4; ++r) {
        float v = acc[mi][ni][r];
        const size_t idx = (size_t)(row0 + r) * ldc + col;
        if constexpr (EPI == 0) {
          C[idx] = v;
        } else if constexpr (EPI == 1) {
          Cb[idx] = f2bf(v);
        } else if constexpr (EPI == 2) {
          v += bias[col];
          v = (v > 20.f) ? v : log1pf(__expf(v));   // softplus
          Cb[idx] = f2bf(v);
        } else {
          C[idx] = v + res[idx];
        }
      }
    }
  }
}

// ---------------- causal depthwise conv (D_CONV=4) + SiLU -> bf16 ----------------
__global__ void conv_silu_k(const float* __restrict__ xz, const float* __restrict__ Wc,
                            const float* __restrict__ bc, u16* __restrict__ ub)
{
  const int gid = blockIdx.x * 256 + threadIdx.x;       // over NTOK*D_INNER
  const int e   = gid & (D_INNER - 1);
  const int tok = gid >> 11;                            // D_INNER = 2^11
  const int l   = tok & (SEQ - 1);
  float acc = bc[e];
  #pragma unroll
  for (int j = 0; j < D_CONV; ++j) {
    const int li = l - 3 + j;
    if (li >= 0) acc += xz[(size_t)(tok - 3 + j) * (2 * D_INNER) + e] * Wc[e * D_CONV + j];
  }
  const float s = acc / (1.f + __expf(-acc));           // silu
  ub[gid] = f2bf(s);
}

// ---------------- selective scan, chunk-parallel (3 passes) ----------------
// Thread layout P1/P3: block = (e-block of 256) x chunk x batch; lane==e (coalesced).
// Each thread owns all 16 states in registers.

// Pass 1: local scan with h=0 -> S[b,c,e,16], sum of delta -> sumd[b,c,e]
__global__ __launch_bounds__(256) void scan_p1(
    const u16* __restrict__ delta, const u16* __restrict__ ub,
    const u16* __restrict__ xdb, const float* __restrict__ A_log,
    float* __restrict__ S, float* __restrict__ sumd)
{
  const int e = blockIdx.x * 256 + threadIdx.x;
  const int c = blockIdx.y;
  const int b = blockIdx.z;
  float A[16], h[16];
  #pragma unroll
  for (int n = 0; n < 16; ++n) { A[n] = -__expf(A_log[e * 16 + n]); h[n] = 0.f; }
  float sd = 0.f;
  const int t0 = c * TCHUNK;
  #pragma unroll 4
  for (int t = 0; t < TCHUNK; ++t) {
    const size_t g = (size_t)(b * SEQ + t0 + t);
    const float dlt = bf2f(delta[g * D_INNER + e]);
    const float ut  = bf2f(ub[g * D_INNER + e]);
    float Bv[16];
    const u16* bp = xdb + g * 128 + DT_RANK;
    unpack8(*(const uint4*)bp, Bv);
    unpack8(*(const uint4*)(bp + 8), Bv + 8);
    sd += dlt;
    const float dbu = dlt * ut;
    #pragma unroll
    for (int n = 0; n < 16; ++n)
      h[n] = __expf(dlt * A[n]) * h[n] + dbu * Bv[n];
  }
  const size_t idx = ((size_t)(b * NCHUNK + c) * D_INNER + e);
  #pragma unroll
  for (int q = 0; q < 4; ++q)
    *(f32x4*)&S[idx * 16 + q * 4] = (f32x4){h[q*4], h[q*4+1], h[q*4+2], h[q*4+3]};
  sumd[idx] = sd;
}

// Pass 2: sequential over chunks -> h_init[b,c,e,16]
__global__ __launch_bounds__(256) void scan_p2(
    const float* __restrict__ S, const float* __restrict__ sumd,
    const float* __restrict__ A_log, float* __restrict__ hinit)
{
  const int tid = blockIdx.x * 256 + threadIdx.x;   // 65536
  const int n = tid & 15;
  const int e = (tid >> 4) & (D_INNER - 1);
  const int b = tid >> 15;
  const float An = -__expf(A_log[e * 16 + n]);
  float h = 0.f;
  size_t idx = (size_t)b * NCHUNK * D_INNER + e;
  float s_cur  = S[idx * 16 + n];
  float sd_cur = sumd[idx];
  for (int c = 0; c < NCHUNK; ++c) {
    hinit[idx * 16 + n] = h;
    float s_nxt = 0.f, sd_nxt = 0.f;
    if (c + 1 < NCHUNK) {
      const size_t idx2 = idx + D_INNER;
      s_nxt  = S[idx2 * 16 + n];
      sd_nxt = sumd[idx2];
    }
    h = __expf(An * sd_cur) * h + s_cur;
    s_cur = s_nxt; sd_cur = sd_nxt;
    idx += D_INNER;
  }
}

// Pass 3: recompute chunk scan from h_init, fused y-dot + skip + gate -> yg (bf16)
__global__ __launch_bounds__(256) void scan_p3(
    const u16* __restrict__ delta, const u16* __restrict__ ub,
    const u16* __restrict__ xdb, const float* __restrict__ xz,
    const float* __restrict__ A_log, const float* __restrict__ D_skip,
    const float* __restrict__ hinit, u16* __restrict__ yg)
{
  const int e = blockIdx.x * 256 + threadIdx.x;
  const int c = blockIdx.y;
  const int b = blockIdx.z;
  const size_t idx = ((size_t)(b * NCHUNK + c) * D_INNER + e);
  float A[16], h[16];
  #pragma unroll
  for (int n = 0; n < 16; ++n) A[n] = -__expf(A_log[e * 16 + n]);
  #pragma unroll
  for (int q = 0; q < 4; ++q) {
    f32x4 v = *(const f32x4*)&hinit[idx * 16 + q * 4];
    h[q*4] = v[0]; h[q*4+1] = v[1]; h[q*4+2] = v[2]; h[q*4+3] = v[3];
  }
  const float De = D_skip[e];
  const int t0 = c * TCHUNK;
  #pragma unroll 2
  for (int t = 0; t < TCHUNK; ++t) {
    const size_t g = (size_t)(b * SEQ + t0 + t);
    const float dlt = bf2f(delta[g * D_INNER + e]);
    const float ut  = bf2f(ub[g * D_INNER + e]);
    const float z   = xz[g * (2 * D_INNER) + D_INNER + e];
    float Bv[16], Cv[16];
    const u16* bp = xdb + g * 128 + DT_RANK;
    unpack8(*(const uint4*)bp, Bv);
    unpack8(*(const uint4*)(bp + 8), Bv + 8);
    unpack8(*(const uint4*)(bp + 16), Cv);
    unpack8(*(const uint4*)(bp + 24), Cv + 8);
    const float dbu = dlt * ut;
    float y = 0.f;
    #pragma unroll
    for (int n = 0; n < 16; ++n) {
      h[n] = __expf(dlt * A[n]) * h[n] + dbu * Bv[n];
      y += h[n] * Cv[n];
    }
    y += ut * De;
    const float gt = z / (1.f + __expf(-z));
    yg[g * D_INNER + e] = f2bf(y * gt);
  }
}

// ---------------- LayerNorm, one block per token ----------------
__global__ __launch_bounds__(256) void ln_k(const float* __restrict__ pre,
                                            const float* __restrict__ gamma,
                                            const float* __restrict__ beta,
                                            float* __restrict__ out)
{
  const int tok = blockIdx.x;
  const int t   = threadIdx.x;
  const float* row = pre + (size_t)tok * D_MODEL;
  float v[4], s = 0.f, s2 = 0.f;
  #pragma unroll
  for (int i = 0; i < 4; ++i) {
    v[i] = row[t + i * 256];
    s += v[i]; s2 += v[i] * v[i];
  }
  #pragma unroll
  for (int off = 32; off >= 1; off >>= 1) {
    s  += __shfl_xor(s,  off);
    s2 += __shfl_xor(s2, off);
  }
  __shared__ float red[8];
  if ((t & 63) == 0) { red[t >> 6] = s; red[4 + (t >> 6)] = s2; }
  __syncthreads();
  if (t == 0) {
    const float ts  = red[0] + red[1] + red[2] + red[3];
    const float ts2 = red[4] + red[5] + red[6] + red[7];
    const float mu  = ts * (1.f / D_MODEL);
    const float var = ts2 * (1.f / D_MODEL) - mu * mu;
    red[0] = mu; red[1] = rsqrtf(var + LN_EPSF);
  }
  __syncthreads();
  const float mu = red[0], rv = red[1];
  #pragma unroll
  for (int i = 0; i < 4; ++i) {
    const int c = t + i * 256;
    out[(size_t)tok * D_MODEL + c] = (v[i] - mu) * rv * gamma[c] + beta[c];
  }
}

// ---------------- host launch ----------------
extern "C" void kernel_launch(void* const* d_in, const int* in_sizes, int n_in,
                              void* d_out, int out_size, void* d_ws, size_t ws_size,
                              hipStream_t stream) {
  const float* x       = (const float*)d_in[0];
  const float* W_in    = (const float*)d_in[1];
  const float* W_conv  = (const float*)d_in[2];
  const float* b_conv  = (const float*)d_in[3];
  const float* W_xproj = (const float*)d_in[4];
  const float* W_dt    = (const float*)d_in[5];
  const float* b_dt    = (const float*)d_in[6];
  const float* A_log   = (const float*)d_in[7];
  const float* D_skip  = (const float*)d_in[8];
  const float* W_out   = (const float*)d_in[9];
  const float* gamma   = (const float*)d_in[10];
  const float* beta    = (const float*)d_in[11];
  float* out = (float*)d_out;

  // workspace carve-up (256B aligned)
  char* ws = (char*)d_ws;
  size_t used = 0;
  auto alloc = [&](size_t bytes) -> char* {
    char* p = ws + used;
    used += (bytes + 255) & ~(size_t)255;
    return p;
  };
  float* xz      = (float*)alloc((size_t)NTOK * 2 * D_INNER * 4);   // 67 MB
  float* pre     = (float*)alloc((size_t)NTOK * D_MODEL * 4);       // 16.8 MB; aliased as S in scan
  char*  xw_reg  = alloc((size_t)16 * 1024 * 1024 + (size_t)NTOK * D_MODEL * 2);
                                                                    // 16.8+8.4: x_bf+Win_bf; aliased as h_init
  u16* u_bf      = (u16*)alloc((size_t)NTOK * D_INNER * 2);         // 16.8 MB
  u16* delta_bf  = (u16*)alloc((size_t)NTOK * D_INNER * 2);         // 16.8 MB
  u16* xdb_bf    = (u16*)alloc((size_t)NTOK * 128 * 2);             // 1 MB (96 padded to 128)
  u16* Wxp_bf    = (u16*)alloc((size_t)128 * D_INNER * 2);          // 0.5 MB
  u16* Wdt_bf    = (u16*)alloc((size_t)D_INNER * DT_RANK * 2);      // 0.26 MB
  u16* Wout_bf   = (u16*)alloc((size_t)D_MODEL * D_INNER * 2);      // 4.2 MB
  u16* yg_bf     = (u16*)alloc((size_t)NTOK * D_INNER * 2);         // 16.8 MB
  float* sumd    = (float*)alloc((size_t)NBATCH * NCHUNK * D_INNER * 4); // 1 MB

  // aliases (time-disjoint usage)
  u16* x_bf    = (u16*)xw_reg;                                    // dead after GEMM1
  u16* Win_bf  = (u16*)(xw_reg + (size_t)NTOK * D_MODEL * 2);     // dead after GEMM1
  float* S     = pre;                                             // pre written at stage 6
  float* hinit = (float*)xw_reg;                                  // needs 16.8 MB

  if (ws_size < used) {   // signal: NaN output (insufficient workspace)
    hipMemsetAsync(d_out, 0xFF, (size_t)out_size * 4, stream);
    return;
  }

  const dim3 blk(256);

  // conversions to bf16
  f32_to_bf16_k<<<(NTOK * D_MODEL + 255) / 256, blk, 0, stream>>>(x, x_bf, NTOK * D_MODEL);
  f32_to_bf16_k<<<(2 * D_INNER * D_MODEL + 255) / 256, blk, 0, stream>>>(W_in, Win_bf, 2 * D_INNER * D_MODEL);
  hipMemsetAsync(Wxp_bf, 0, (size_t)128 * D_INNER * 2, stream);
  f32_to_bf16_k<<<(96 * D_INNER + 255) / 256, blk, 0, stream>>>(W_xproj, Wxp_bf, 96 * D_INNER);
  f32_to_bf16_k<<<(D_INNER * DT_RANK + 255) / 256, blk, 0, stream>>>(W_dt, Wdt_bf, D_INNER * DT_RANK);
  f32_to_bf16_k<<<(D_MODEL * D_INNER + 255) / 256, blk, 0, stream>>>(W_out, Wout_bf, D_MODEL * D_INNER);

  // 1) in_proj: xz[4096,4096] = x[4096,1024] * W_in[4096,1024]^T
  gemm_nt<128,128,4,4,0><<<dim3((2*D_INNER)/128, NTOK/128), blk, 0, stream>>>(
      x_bf, Win_bf, xz, nullptr, nullptr, nullptr, D_MODEL, D_MODEL, D_MODEL, 2*D_INNER);

  // 2) causal depthwise conv + silu -> u (bf16)
  conv_silu_k<<<(NTOK * D_INNER) / 256, blk, 0, stream>>>(xz, W_conv, b_conv, u_bf);

  // 3) x_proj: xdb[4096,128(pad)] = u * W_xproj^T  (bf16 out)
  gemm_nt<64,128,1,8,1><<<dim3(1, NTOK/64), blk, 0, stream>>>(
      u_bf, Wxp_bf, nullptr, xdb_bf, nullptr, nullptr, D_INNER, D_INNER, D_INNER, 128);

  // 4) dt_proj + bias + softplus: delta[4096,2048] = softplus(dt * W_dt^T + b_dt) -> bf16
  gemm_nt<128,128,4,4,2><<<dim3(D_INNER/128, NTOK/128), blk, 0, stream>>>(
      xdb_bf, Wdt_bf, nullptr, delta_bf, b_dt, nullptr, DT_RANK, 128, DT_RANK, D_INNER);

  // 5) chunk-parallel selective scan + skip + gate -> yg (bf16)
  scan_p1<<<dim3(D_INNER/256, NCHUNK, NBATCH), blk, 0, stream>>>(
      delta_bf, u_bf, xdb_bf, A_log, S, sumd);
  scan_p2<<<(NBATCH * D_INNER * D_STATE) / 256, blk, 0, stream>>>(
      S, sumd, A_log, hinit);
  scan_p3<<<dim3(D_INNER/256, NCHUNK, NBATCH), blk, 0, stream>>>(
      delta_bf, u_bf, xdb_bf, xz, A_log, D_skip, hinit, yg_bf);

  // 6) out_proj + residual: pre[4096,1024] = yg * W_out^T + x
  gemm_nt<128,128,4,4,3><<<dim3(D_MODEL/128, NTOK/128), blk, 0, stream>>>(
      yg_bf, Wout_bf, pre, nullptr, nullptr, x, D_INNER, D_INNER, D_INNER, D_MODEL);

  // 7) LayerNorm
  ln_k<<<NTOK, blk, 0, stream>>>(pre, gamma, beta, out);
}

// Round 4
// 383.717 us; speedup vs baseline: 5.7034x; 1.0495x over previous
//
#include <hip/hip_runtime.h>
#include <cstdint>
#include <cstddef>

// ---------------- problem constants ----------------
#define D_MODEL   1024
#define D_STATE   16
#define D_CONV    4
#define D_INNER   2048
#define DT_RANK   64
#define NBATCH    2
#define SEQ       2048
#define NTOK      (NBATCH*SEQ)     // 4096 tokens
#define LN_EPSF   1e-5f
#define NCHUNK    64
#define TCHUNK    32               // SEQ / NCHUNK
#define KSPLIT    8                // x_proj split-K factor

typedef unsigned short u16;
typedef __bf16 bf16x8 __attribute__((ext_vector_type(8)));
typedef float  f32x4  __attribute__((ext_vector_type(4)));

__device__ __forceinline__ u16 f2bf(float f) {
  unsigned u = __float_as_uint(f);
  u += 0x7fffu + ((u >> 16) & 1u);          // round-to-nearest-even
  return (u16)(u >> 16);
}
__device__ __forceinline__ float bf2f(u16 v) {
  return __uint_as_float(((unsigned)v) << 16);
}
// unpack 8 bf16 (packed in uint4) -> 8 floats
__device__ __forceinline__ void unpack8(uint4 v, float* f) {
  f[0] = __uint_as_float(v.x << 16); f[1] = __uint_as_float(v.x & 0xffff0000u);
  f[2] = __uint_as_float(v.y << 16); f[3] = __uint_as_float(v.y & 0xffff0000u);
  f[4] = __uint_as_float(v.z << 16); f[5] = __uint_as_float(v.z & 0xffff0000u);
  f[6] = __uint_as_float(v.w << 16); f[7] = __uint_as_float(v.w & 0xffff0000u);
}

// async global->LDS, 16B per lane; lds dest must be wave-uniform base (+lane*16)
__device__ __forceinline__ void async16(const u16* g, u16* l) {
  __builtin_amdgcn_global_load_lds(
      (const __attribute__((address_space(1))) unsigned*)g,
      (__attribute__((address_space(3))) unsigned*)l, 16, 0, 0);
}

// ---------------- fused prep: all f32->bf16 weight/input conversions ----------------
#define PN0 (NTOK*D_MODEL)          // x
#define PN1 (2*D_INNER*D_MODEL)     // W_in
#define PN2 (128*D_INNER)           // W_xproj (padded 96->128 rows)
#define PN3 (D_INNER*DT_RANK)       // W_dt
#define PN4 (D_MODEL*D_INNER)       // W_out
#define PTOT (PN0+PN1+PN2+PN3+PN4)
__global__ __launch_bounds__(256) void prep_k(
    const float* __restrict__ x, const float* __restrict__ W_in,
    const float* __restrict__ W_xproj, const float* __restrict__ W_dt,
    const float* __restrict__ W_out,
    u16* __restrict__ x_bf, u16* __restrict__ Win_bf, u16* __restrict__ Wxp_bf,
    u16* __restrict__ Wdt_bf, u16* __restrict__ Wout_bf)
{
  int i = blockIdx.x * 256 + threadIdx.x;
  if (i < PN0) { x_bf[i] = f2bf(x[i]); return; }
  i -= PN0;
  if (i < PN1) { Win_bf[i] = f2bf(W_in[i]); return; }
  i -= PN1;
  if (i < PN2) {
    const int f = i >> 11;                    // row over 2048 cols
    Wxp_bf[i] = (f < 96) ? f2bf(W_xproj[i]) : (u16)0;
    return;
  }
  i -= PN2;
  if (i < PN3) { Wdt_bf[i] = f2bf(W_dt[i]); return; }
  i -= PN3;
  if (i < PN4) { Wout_bf[i] = f2bf(W_out[i]); }
}

// ---------------- bf16 NT GEMM: C[M,N] = A[M,K] * B[N,K]^T ----------------
// EPI: 0=f32 store, 1=bf16 store, 2=softplus(acc+bias[col])->bf16, 3=acc+res f32,
//      4=f32 store into partial plane blockIdx.z (split-K; K range shifts by z)
template<int BM, int BN, int WTM, int WTN, int EPI>
__global__ __launch_bounds__(256) void gemm_nt(
    const u16* __restrict__ A, const u16* __restrict__ B,
    float* __restrict__ C, u16* __restrict__ Cb,
    const float* __restrict__ bias, const float* __restrict__ res,
    int kStart, int kEnd, int lda, int ldb, int ldc, size_t partStride)
{
  constexpr int BK = 32;
  constexpr int WAVES_N = BN / (16 * WTN);
  constexpr int ACH = BM * 4;             // 16B chunks in A tile (BK=32 bf16 = 4 chunks/row)
  constexpr int BCH = BN * 4;
  constexpr int ROUNDS = (ACH + BCH) / 256;

  __shared__ __align__(16) u16 lA[BM * BK];
  __shared__ __align__(16) u16 lB[BN * BK];

  const int tid  = threadIdx.x;
  const int w    = tid >> 6;
  const int lane = tid & 63;
  const int lrow = lane & 15;
  const int quad = lane >> 4;
  const int bm = blockIdx.y * BM;
  const int bn = blockIdx.x * BN;
  const int wave_m = (w / WAVES_N) * (16 * WTM);
  const int wave_n = (w % WAVES_N) * (16 * WTN);

  int kOff = 0;
  if constexpr (EPI == 4) kOff = blockIdx.z * (kEnd - kStart);

  f32x4 acc[WTM][WTN];
  #pragma unroll
  for (int mi = 0; mi < WTM; ++mi)
    #pragma unroll
    for (int ni = 0; ni < WTN; ++ni)
      acc[mi][ni] = (f32x4){0.f, 0.f, 0.f, 0.f};

  for (int k0 = kStart + kOff; k0 < kEnd + kOff; k0 += BK) {
    #pragma unroll
    for (int r = 0; r < ROUNDS; ++r) {
      const int c0 = r * 256 + w * 64;    // wave-uniform chunk base
      const int c  = c0 + lane;
      if (c0 < ACH) {
        const int row = c >> 2, cc = c & 3;
        async16(A + (size_t)(bm + row) * lda + k0 + cc * 8, &lA[c0 * 8]);
      } else {
        const int cb = c - ACH, c0b = c0 - ACH;
        const int row = cb >> 2, cc = cb & 3;
        async16(B + (size_t)(bn + row) * ldb + k0 + cc * 8, &lB[c0b * 8]);
      }
    }
    __syncthreads();   // drain global_load_lds + join

    bf16x8 af[WTM], bfv[WTN];
    #pragma unroll
    for (int mi = 0; mi < WTM; ++mi)
      af[mi] = *(const bf16x8*)&lA[(wave_m + mi * 16 + lrow) * BK + quad * 8];
    #pragma unroll
    for (int ni = 0; ni < WTN; ++ni)
      bfv[ni] = *(const bf16x8*)&lB[(wave_n + ni * 16 + lrow) * BK + quad * 8];
    #pragma unroll
    for (int mi = 0; mi < WTM; ++mi)
      #pragma unroll
      for (int ni = 0; ni < WTN; ++ni)
        acc[mi][ni] = __builtin_amdgcn_mfma_f32_16x16x32_bf16(af[mi], bfv[ni], acc[mi][ni], 0, 0, 0);
    __syncthreads();   // all waves done reading before next overwrite
  }

  #pragma unroll
  for (int mi = 0; mi < WTM; ++mi) {
    #pragma unroll
    for (int ni = 0; ni < WTN; ++ni) {
      const int col  = bn + wave_n + ni * 16 + lrow;
      const int row0 = bm + wave_m + mi * 16 + quad * 4;
      #pragma unroll
      for (int r = 0; r < 4; ++r) {
        float v = acc[mi][ni][r];
        const size_t idx = (size_t)(row0 + r) * ldc + col;
        if constexpr (EPI == 0) {
          C[idx] = v;
        } else if constexpr (EPI == 1) {
          Cb[idx] = f2bf(v);
        } else if constexpr (EPI == 2) {
          v += bias[col];
          v = (v > 20.f) ? v : log1pf(__expf(v));   // softplus
          Cb[idx] = f2bf(v);
        } else if constexpr (EPI == 3) {
          C[idx] = v + res[idx];
        } else {
          C[(size_t)blockIdx.z * partStride + idx] = v;
        }
      }
    }
  }
}

// ---------------- split-K reduce + bf16 convert (x_proj) ----------------
__global__ __launch_bounds__(256) void reduce_conv_k(
    const float* __restrict__ part, u16* __restrict__ dst)
{
  const int i = blockIdx.x * 256 + threadIdx.x;     // over NTOK*128
  float s = 0.f;
  #pragma unroll
  for (int p = 0; p < KSPLIT; ++p)
    s += part[(size_t)p * (NTOK * 128) + i];
  dst[i] = f2bf(s);
}

// ---------------- causal depthwise conv (D_CONV=4) + SiLU -> bf16 ----------------
__global__ void conv_silu_k(const u16* __restrict__ xz, const float* __restrict__ Wc,
                            const float* __restrict__ bc, u16* __restrict__ ub)
{
  const int gid = blockIdx.x * 256 + threadIdx.x;       // over NTOK*D_INNER
  const int e   = gid & (D_INNER - 1);
  const int tok = gid >> 11;                            // D_INNER = 2^11
  const int l   = tok & (SEQ - 1);
  float acc = bc[e];
  #pragma unroll
  for (int j = 0; j < D_CONV; ++j) {
    const int li = l - 3 + j;
    if (li >= 0) acc += bf2f(xz[(size_t)(tok - 3 + j) * (2 * D_INNER) + e]) * Wc[e * D_CONV + j];
  }
  const float s = acc / (1.f + __expf(-acc));           // silu
  ub[gid] = f2bf(s);
}

// ---------------- selective scan, chunk-parallel (3 passes) ----------------
// Pass 1: local scan with h=0 -> S[b,c,e,16], sum of delta -> sumd[b,c,e]
__global__ __launch_bounds__(256) void scan_p1(
    const u16* __restrict__ delta, const u16* __restrict__ ub,
    const u16* __restrict__ xdb, const float* __restrict__ A_log,
    float* __restrict__ S, float* __restrict__ sumd)
{
  const int e = blockIdx.x * 256 + threadIdx.x;
  const int c = blockIdx.y;
  const int b = blockIdx.z;
  float A[16], h[16];
  #pragma unroll
  for (int n = 0; n < 16; ++n) { A[n] = -__expf(A_log[e * 16 + n]); h[n] = 0.f; }
  float sd = 0.f;
  const int t0 = c * TCHUNK;
  #pragma unroll 4
  for (int t = 0; t < TCHUNK; ++t) {
    const size_t g = (size_t)(b * SEQ + t0 + t);
    const float dlt = bf2f(delta[g * D_INNER + e]);
    const float ut  = bf2f(ub[g * D_INNER + e]);
    float Bv[16];
    const u16* bp = xdb + g * 128 + DT_RANK;
    unpack8(*(const uint4*)bp, Bv);
    unpack8(*(const uint4*)(bp + 8), Bv + 8);
    sd += dlt;
    const float dbu = dlt * ut;
    #pragma unroll
    for (int n = 0; n < 16; ++n)
      h[n] = __expf(dlt * A[n]) * h[n] + dbu * Bv[n];
  }
  const size_t idx = ((size_t)(b * NCHUNK + c) * D_INNER + e);
  #pragma unroll
  for (int q = 0; q < 4; ++q)
    *(f32x4*)&S[idx * 16 + q * 4] = (f32x4){h[q*4], h[q*4+1], h[q*4+2], h[q*4+3]};
  sumd[idx] = sd;
}

// Pass 2: sequential over chunks -> h_init[b,c,e,16]
__global__ __launch_bounds__(256) void scan_p2(
    const float* __restrict__ S, const float* __restrict__ sumd,
    const float* __restrict__ A_log, float* __restrict__ hinit)
{
  const int tid = blockIdx.x * 256 + threadIdx.x;   // 65536
  const int n = tid & 15;
  const int e = (tid >> 4) & (D_INNER - 1);
  const int b = tid >> 15;
  const float An = -__expf(A_log[e * 16 + n]);
  float h = 0.f;
  size_t idx = (size_t)b * NCHUNK * D_INNER + e;
  float s_cur  = S[idx * 16 + n];
  float sd_cur = sumd[idx];
  for (int c = 0; c < NCHUNK; ++c) {
    hinit[idx * 16 + n] = h;
    float s_nxt = 0.f, sd_nxt = 0.f;
    if (c + 1 < NCHUNK) {
      const size_t idx2 = idx + D_INNER;
      s_nxt  = S[idx2 * 16 + n];
      sd_nxt = sumd[idx2];
    }
    h = __expf(An * sd_cur) * h + s_cur;
    s_cur = s_nxt; sd_cur = sd_nxt;
    idx += D_INNER;
  }
}

// Pass 3: recompute chunk scan from h_init, fused y-dot + skip + gate -> yg (bf16)
__global__ __launch_bounds__(256) void scan_p3(
    const u16* __restrict__ delta, const u16* __restrict__ ub,
    const u16* __restrict__ xdb, const u16* __restrict__ xz,
    const float* __restrict__ A_log, const float* __restrict__ D_skip,
    const float* __restrict__ hinit, u16* __restrict__ yg)
{
  const int e = blockIdx.x * 256 + threadIdx.x;
  const int c = blockIdx.y;
  const int b = blockIdx.z;
  const size_t idx = ((size_t)(b * NCHUNK + c) * D_INNER + e);
  float A[16], h[16];
  #pragma unroll
  for (int n = 0; n < 16; ++n) A[n] = -__expf(A_log[e * 16 + n]);
  #pragma unroll
  for (int q = 0; q < 4; ++q) {
    f32x4 v = *(const f32x4*)&hinit[idx * 16 + q * 4];
    h[q*4] = v[0]; h[q*4+1] = v[1]; h[q*4+2] = v[2]; h[q*4+3] = v[3];
  }
  const float De = D_skip[e];
  const int t0 = c * TCHUNK;
  #pragma unroll 2
  for (int t = 0; t < TCHUNK; ++t) {
    const size_t g = (size_t)(b * SEQ + t0 + t);
    const float dlt = bf2f(delta[g * D_INNER + e]);
    const float ut  = bf2f(ub[g * D_INNER + e]);
    const float z   = bf2f(xz[g * (2 * D_INNER) + D_INNER + e]);
    float Bv[16], Cv[16];
    const u16* bp = xdb + g * 128 + DT_RANK;
    unpack8(*(const uint4*)bp, Bv);
    unpack8(*(const uint4*)(bp + 8), Bv + 8);
    unpack8(*(const uint4*)(bp + 16), Cv);
    unpack8(*(const uint4*)(bp + 24), Cv + 8);
    const float dbu = dlt * ut;
    float y = 0.f;
    #pragma unroll
    for (int n = 0; n < 16; ++n) {
      h[n] = __expf(dlt * A[n]) * h[n] + dbu * Bv[n];
      y += h[n] * Cv[n];
    }
    y += ut * De;
    const float gt = z / (1.f + __expf(-z));
    yg[g * D_INNER + e] = f2bf(y * gt);
  }
}

// ---------------- LayerNorm, one block per token ----------------
__global__ __launch_bounds__(256) void ln_k(const float* __restrict__ pre,
                                            const float* __restrict__ gamma,
                                            const float* __restrict__ beta,
                                            float* __restrict__ out)
{
  const int tok = blockIdx.x;
  const int t   = threadIdx.x;
  const float* row = pre + (size_t)tok * D_MODEL;
  float v[4], s = 0.f, s2 = 0.f;
  #pragma unroll
  for (int i = 0; i < 4; ++i) {
    v[i] = row[t + i * 256];
    s += v[i]; s2 += v[i] * v[i];
  }
  #pragma unroll
  for (int off = 32; off >= 1; off >>= 1) {
    s  += __shfl_xor(s,  off);
    s2 += __shfl_xor(s2, off);
  }
  __shared__ float red[8];
  if ((t & 63) == 0) { red[t >> 6] = s; red[4 + (t >> 6)] = s2; }
  __syncthreads();
  if (t == 0) {
    const float ts  = red[0] + red[1] + red[2] + red[3];
    const float ts2 = red[4] + red[5] + red[6] + red[7];
    const float mu  = ts * (1.f / D_MODEL);
    const float var = ts2 * (1.f / D_MODEL) - mu * mu;
    red[0] = mu; red[1] = rsqrtf(var + LN_EPSF);
  }
  __syncthreads();
  const float mu = red[0], rv = red[1];
  #pragma unroll
  for (int i = 0; i < 4; ++i) {
    const int c = t + i * 256;
    out[(size_t)tok * D_MODEL + c] = (v[i] - mu) * rv * gamma[c] + beta[c];
  }
}

// ---------------- host launch ----------------
extern "C" void kernel_launch(void* const* d_in, const int* in_sizes, int n_in,
                              void* d_out, int out_size, void* d_ws, size_t ws_size,
                              hipStream_t stream) {
  const float* x       = (const float*)d_in[0];
  const float* W_in    = (const float*)d_in[1];
  const float* W_conv  = (const float*)d_in[2];
  const float* b_conv  = (const float*)d_in[3];
  const float* W_xproj = (const float*)d_in[4];
  const float* W_dt    = (const float*)d_in[5];
  const float* b_dt    = (const float*)d_in[6];
  const float* A_log   = (const float*)d_in[7];
  const float* D_skip  = (const float*)d_in[8];
  const float* W_out   = (const float*)d_in[9];
  const float* gamma   = (const float*)d_in[10];
  const float* beta    = (const float*)d_in[11];
  float* out = (float*)d_out;

  // workspace carve-up (256B aligned)
  char* ws = (char*)d_ws;
  size_t used = 0;
  auto alloc = [&](size_t bytes) -> char* {
    char* p = ws + used;
    used += (bytes + 255) & ~(size_t)255;
    return p;
  };
  u16* xz_bf     = (u16*)alloc((size_t)NTOK * 2 * D_INNER * 2);     // 33.5 MB
  float* pre     = (float*)alloc((size_t)NTOK * D_MODEL * 4);       // 16.8 MB; alias S
  char*  xw_reg  = alloc((size_t)NTOK * D_MODEL * 2 + (size_t)2 * D_INNER * D_MODEL * 2);
                                                                    // x_bf+Win_bf 16.8 MB; alias hinit
  u16* u_bf      = (u16*)alloc((size_t)NTOK * D_INNER * 2);         // 16.8 MB
  u16* delta_bf  = (u16*)alloc((size_t)NTOK * D_INNER * 2);         // 16.8 MB
  u16* xdb_bf    = (u16*)alloc((size_t)NTOK * 128 * 2);             // 1 MB (96 padded to 128)
  u16* Wxp_bf    = (u16*)alloc((size_t)128 * D_INNER * 2);          // 0.5 MB
  u16* Wdt_bf    = (u16*)alloc((size_t)D_INNER * DT_RANK * 2);      // 0.26 MB
  u16* Wout_bf   = (u16*)alloc((size_t)D_MODEL * D_INNER * 2);      // 4.2 MB
  u16* yg_bf     = (u16*)alloc((size_t)NTOK * D_INNER * 2);         // 16.8 MB
  float* sumd    = (float*)alloc((size_t)NBATCH * NCHUNK * D_INNER * 4); // 1 MB
  float* xdb_part= (float*)alloc((size_t)KSPLIT * NTOK * 128 * 4);  // 16.8 MB

  // aliases (time-disjoint usage)
  u16* x_bf    = (u16*)xw_reg;                                    // dead after GEMM1
  u16* Win_bf  = (u16*)(xw_reg + (size_t)NTOK * D_MODEL * 2);     // dead after GEMM1
  float* S     = pre;                                             // pre written at stage 6
  float* hinit = (float*)xw_reg;                                  // 16.8 MB, after GEMM1

  if (ws_size < used) {   // signal: NaN output (insufficient workspace)
    hipMemsetAsync(d_out, 0xFF, (size_t)out_size * 4, stream);
    return;
  }

  const dim3 blk(256);

  // 0) all f32->bf16 conversions in one kernel
  prep_k<<<(PTOT + 255) / 256, blk, 0, stream>>>(
      x, W_in, W_xproj, W_dt, W_out, x_bf, Win_bf, Wxp_bf, Wdt_bf, Wout_bf);

  // 1) in_proj: xz[4096,4096] = x[4096,1024] * W_in[4096,1024]^T  (bf16 out)
  gemm_nt<128,128,4,4,1><<<dim3((2*D_INNER)/128, NTOK/128), blk, 0, stream>>>(
      x_bf, Win_bf, nullptr, xz_bf, nullptr, nullptr,
      0, D_MODEL, D_MODEL, D_MODEL, 2*D_INNER, 0);

  // 2) causal depthwise conv + silu -> u (bf16)
  conv_silu_k<<<(NTOK * D_INNER) / 256, blk, 0, stream>>>(xz_bf, W_conv, b_conv, u_bf);

  // 3) x_proj split-K=8: partials[8][4096][128] = u * W_xproj^T
  gemm_nt<64,128,1,8,4><<<dim3(1, NTOK/64, KSPLIT), blk, 0, stream>>>(
      u_bf, Wxp_bf, xdb_part, nullptr, nullptr, nullptr,
      0, D_INNER / KSPLIT, D_INNER, D_INNER, 128, (size_t)NTOK * 128);
  reduce_conv_k<<<(NTOK * 128) / 256, blk, 0, stream>>>(xdb_part, xdb_bf);

  // 4) dt_proj + bias + softplus: delta[4096,2048] -> bf16
  gemm_nt<128,128,4,4,2><<<dim3(D_INNER/128, NTOK/128), blk, 0, stream>>>(
      xdb_bf, Wdt_bf, nullptr, delta_bf, b_dt, nullptr,
      0, DT_RANK, 128, DT_RANK, D_INNER, 0);

  // 5) chunk-parallel selective scan + skip + gate -> yg (bf16)
  scan_p1<<<dim3(D_INNER/256, NCHUNK, NBATCH), blk, 0, stream>>>(
      delta_bf, u_bf, xdb_bf, A_log, S, sumd);
  scan_p2<<<(NBATCH * D_INNER * D_STATE) / 256, blk, 0, stream>>>(
      S, sumd, A_log, hinit);
  scan_p3<<<dim3(D_INNER/256, NCHUNK, NBATCH), blk, 0, stream>>>(
      delta_bf, u_bf, xdb_bf, xz_bf, A_log, D_skip, hinit, yg_bf);

  // 6) out_proj + residual: pre[4096,1024] = yg * W_out^T + x   (128x64 tiles, 512 blocks)
  gemm_nt<128,64,4,2,3><<<dim3(D_MODEL/64, NTOK/128), blk, 0, stream>>>(
      yg_bf, Wout_bf, pre, nullptr, nullptr, x,
      0, D_INNER, D_INNER, D_INNER, D_MODEL, 0);

  // 7) LayerNorm
  ln_k<<<NTOK, blk, 0, stream>>>(pre, gamma, beta, out);
}